// Round 2
// baseline (6907.429 us; speedup 1.0000x reference)
//
#include <hip/hip_runtime.h>
#include <hip/hip_bf16.h>
#include <hip/hip_cooperative_groups.h>
#include <stdint.h>

namespace cg = cooperative_groups;

typedef __hip_bfloat16 bf16_t;
typedef __attribute__((ext_vector_type(4))) float f32x4;
typedef __attribute__((ext_vector_type(8))) short s16x8;

#define UNITS 768
#define NCOLS 3072        // 4*UNITS (gates, reordered)
#define NPRED 96
#define NPAD  3200        // 25 tiles of 128
#define MROWS 2048
#define BM 128
#define BN 128
#define BK 32

// async global->LDS, 16B per lane, LDS dest = wave-uniform base + lane*16
#define GLL16(ldsp, gp) \
  __builtin_amdgcn_global_load_lds((const __attribute__((address_space(1))) void*)(gp), \
                                   (__attribute__((address_space(3))) void*)(ldsp), 16, 0, 0)

__device__ __forceinline__ float sigf(float x) {
    return __builtin_amdgcn_rcpf(1.f + __expf(-x));
}
__device__ __forceinline__ float tanh_fast(float x) {
    return 1.f - 2.f * __builtin_amdgcn_rcpf(1.f + __expf(2.f * x));
}

// ---------------- prep kernels (once per launch, off critical path) ---------------

// B0T[c][k] = W_ih[g*768+u][k], c-reordered, K=96
__global__ void prep_b0(const float* __restrict__ W_ih, bf16_t* __restrict__ B0T) {
    int idx = blockIdx.x * 256 + threadIdx.x;
    if (idx >= NCOLS * 96) return;
    int c = idx / 96, k = idx % 96;
    int u = ((c >> 6) << 4) + (c & 15);
    int g = (c >> 4) & 3;
    B0T[idx] = (bf16_t)W_ih[(g * UNITS + u) * 96 + k];
}

// x0[b][k] = inputs[b][23][k]
__global__ void prep_x0(const float* __restrict__ inputs, bf16_t* __restrict__ x0) {
    int idx = blockIdx.x * 256 + threadIdx.x; // < 2048*96 exactly
    int b = idx / 96, k = idx % 96;
    x0[idx] = (bf16_t)inputs[(b * 24 + 23) * 96 + k];
}

// b0_r[c] = b_ih+b_hh (reordered); beff_r[c] = b0_r + (W_ih @ b_d)
__global__ void prep_bias(const float* __restrict__ b_ih, const float* __restrict__ b_hh,
                          const float* __restrict__ W_ih, const float* __restrict__ b_d,
                          float* __restrict__ b0_r, float* __restrict__ beff_r) {
    int c = blockIdx.x * 256 + threadIdx.x;
    if (c >= NCOLS) return;
    int u = ((c >> 6) << 4) + (c & 15);
    int g = (c >> 4) & 3;
    int r = g * UNITS + u;
    float v = b_ih[r] + b_hh[r];
    float acc = 0.f;
    for (int j = 0; j < 96; ++j) acc += W_ih[r * 96 + j] * b_d[j];
    b0_r[c] = v;
    beff_r[c] = v + acc;
}

// BeffT[c][k] = W_hh[r(c)][k] + sum_j W_ih[r(c)][j]*W_d[j][k]   (c<3072, LDS-tiled)
__global__ void prep_beff2(const float* __restrict__ W_hh, const float* __restrict__ W_ih,
                           const float* __restrict__ W_d, bf16_t* __restrict__ BeffT) {
    __shared__ float sWih[64][96];
    __shared__ float sWd[96][64];
    const int c0 = blockIdx.x * 64, k0 = blockIdx.y * 64;
    const int tid = threadIdx.x;
    for (int i = tid; i < 64 * 96; i += 256) {
        int cc = i / 96, j = i % 96;
        int c = c0 + cc;
        int u = ((c >> 6) << 4) + (c & 15);
        int g = (c >> 4) & 3;
        sWih[cc][j] = W_ih[(g * UNITS + u) * 96 + j];
    }
    for (int i = tid; i < 96 * 64; i += 256) {
        int j = i / 64, kk = i % 64;
        sWd[j][kk] = W_d[j * UNITS + k0 + kk];
    }
    __syncthreads();
    const int kk = tid & 63;
    const int cc0 = (tid >> 6) * 16;
    for (int cc = cc0; cc < cc0 + 16; ++cc) {
        float acc = 0.f;
#pragma unroll 12
        for (int j = 0; j < 96; ++j) acc += sWih[cc][j] * sWd[j][kk];
        int c = c0 + cc;
        int u = ((c >> 6) << 4) + (c & 15);
        int g = (c >> 4) & 3;
        int r = g * UNITS + u;
        BeffT[(size_t)c * UNITS + k0 + kk] = (bf16_t)(W_hh[(size_t)r * UNITS + k0 + kk] + acc);
    }
}

// rows 3072..3199 of BeffT: W_d rows then zero pad
__global__ void prep_wdt(const float* __restrict__ W_d, bf16_t* __restrict__ BeffT) {
    int idx = blockIdx.x * 256 + threadIdx.x; // 128*768
    int c = idx / UNITS, k = idx % UNITS;
    float v = (c < NPRED) ? W_d[c * UNITS + k] : 0.f;
    BeffT[(size_t)(NCOLS + c) * UNITS + k] = (bf16_t)v;
}

// ---------------- persistent cooperative kernel: all 64 steps ---------------
// grid = 400 blocks: nt = blk/16 (0..24), mt = blk%16. nt<24: gate tile (c-state in
// registers, persistent); nt==24: pred tile -> out.
__global__ __launch_bounds__(256, 2)
void persistent_kernel(const bf16_t* __restrict__ x0,
                       const bf16_t* __restrict__ B0T,
                       const bf16_t* __restrict__ BeffT,
                       const float* __restrict__ b0r,
                       const float* __restrict__ beffr,
                       const float* __restrict__ b_d,
                       bf16_t* __restrict__ h0,
                       bf16_t* __restrict__ h1,
                       float* __restrict__ out)
{
    cg::grid_group grid = cg::this_grid();

    __shared__ bf16_t sA[BM * BK];
    __shared__ bf16_t sB[BN * BK];

    const int tid = threadIdx.x;
    const int wave = tid >> 6;
    const int lane = tid & 63;
    const int wr = wave >> 1, wc = wave & 1;
    const int l15 = lane & 15, l4 = lane >> 4;

    const int blk = blockIdx.x;
    const int nt = blk / 16;
    const int mt = blk % 16;
    const int m0 = mt * BM;
    const int n0 = nt * BN;
    const bool is_pred = (nt == 24);

    bf16_t* hbuf[2] = {h0, h1};

    // persistent per-lane state / constants
    float creg[16];
#pragma unroll
    for (int i = 0; i < 16; ++i) creg[i] = 0.f;

    float bi0[4], bie[4], bd[4];
    const int u = nt * 32 + wc * 16 + l15;
    if (!is_pred) {
#pragma unroll
        for (int f = 0; f < 4; ++f) {
            bi0[f] = b0r[n0 + wc * 64 + f * 16 + l15];
            bie[f] = beffr[n0 + wc * 64 + f * 16 + l15];
        }
    } else {
#pragma unroll
        for (int f = 0; f < 4; ++f) {
            int j = wc * 64 + f * 16 + l15;
            bd[f] = (j < NPRED) ? b_d[j] : 0.f;
        }
    }

    const int o0 = wave * 1024 + lane * 16;   // byte offset within 8KB tile
    const char* sAc = (const char*)sA;
    const char* sBc = (const char*)sB;

    for (int n = 0; n <= 64; ++n) {
        const bool active = (n == 0) ? (!is_pred) : ((n == 64) ? is_pred : true);
        if (active) {
            const bf16_t* A  = (n == 0) ? x0 : hbuf[n & 1];
            const bf16_t* Bm = (n == 0) ? B0T : BeffT;
            const int Kdim   = (n == 0) ? 96 : UNITS;
            const int nk = Kdim >> 5;

            f32x4 acc[4][4];
#pragma unroll
            for (int i = 0; i < 4; ++i)
#pragma unroll
                for (int j = 0; j < 4; ++j) acc[i][j] = f32x4{0.f, 0.f, 0.f, 0.f};

            for (int kt = 0; kt < nk; ++kt) {
                const int k0 = kt << 5;
#pragma unroll
                for (int r = 0; r < 2; ++r) {
                    int ob = o0 + r * 4096;
                    int row = ob >> 6;
                    int kb = ob & 63;
                    const bf16_t* gA = A + (size_t)(m0 + row) * Kdim + k0 + (kb >> 1);
                    GLL16(sA + ((wave * 1024 + r * 4096) >> 1), gA);
                    const bf16_t* gB = Bm + (size_t)(n0 + row) * Kdim + k0 + (kb >> 1);
                    GLL16(sB + ((wave * 1024 + r * 4096) >> 1), gB);
                }
                __syncthreads();

                s16x8 af[4], bfr[4];
#pragma unroll
                for (int f = 0; f < 4; ++f) {
                    af[f]  = *(const s16x8*)(sAc + (wr * 64 + f * 16 + l15) * 64 + l4 * 16);
                    bfr[f] = *(const s16x8*)(sBc + (wc * 64 + f * 16 + l15) * 64 + l4 * 16);
                }
#pragma unroll
                for (int i = 0; i < 4; ++i)
#pragma unroll
                    for (int j = 0; j < 4; ++j)
                        acc[i][j] = __builtin_amdgcn_mfma_f32_16x16x32_bf16(af[i], bfr[j], acc[i][j], 0, 0, 0);
                __syncthreads();
            }

            if (!is_pred) {
                bf16_t* h_out = hbuf[(n + 1) & 1];
                const float* bi = (n == 0) ? bi0 : bie;
#pragma unroll
                for (int i = 0; i < 4; ++i) {
#pragma unroll
                    for (int r = 0; r < 4; ++r) {
                        int row = m0 + wr * 64 + i * 16 + l4 * 4 + r;
                        float gi = acc[i][0][r] + bi[0];
                        float gf = acc[i][1][r] + bi[1];
                        float gg = acc[i][2][r] + bi[2];
                        float go = acc[i][3][r] + bi[3];
                        float si = sigf(gi);
                        float sf = sigf(gf);
                        float tg = tanh_fast(gg);
                        float so = sigf(go);
                        float cn = sf * creg[i * 4 + r] + si * tg;
                        creg[i * 4 + r] = cn;
                        h_out[(size_t)row * UNITS + u] = (bf16_t)(so * tanh_fast(cn));
                    }
                }
            } else {
                const int t = n - 1;
#pragma unroll
                for (int f = 0; f < 4; ++f) {
                    int j = wc * 64 + f * 16 + l15;
                    if (j < NPRED) {
#pragma unroll
                        for (int i = 0; i < 4; ++i)
#pragma unroll
                            for (int r = 0; r < 4; ++r) {
                                int row = m0 + wr * 64 + i * 16 + l4 * 4 + r;
                                out[((size_t)row * 64 + t) * NPRED + j] = acc[i][f][r] + bd[f];
                            }
                    }
                }
            }
        }
        if (n < 64) {
            __threadfence();
            grid.sync();
        }
    }
}

// ---------------- fallback per-step kernel (verified R0 path) ---------------
__global__ __launch_bounds__(256, 2)
void step_kernel(const bf16_t* __restrict__ A,
                 const bf16_t* __restrict__ BT,
                 const float* __restrict__ bias_r,
                 const float* __restrict__ b_d,
                 float* __restrict__ c_state,
                 bf16_t* __restrict__ h_out,
                 float* __restrict__ out,
                 int Kdim, int col_tile_base, int t, int is_first)
{
    __shared__ bf16_t sA[BM * BK];
    __shared__ bf16_t sB[BN * BK];

    const int tid = threadIdx.x;
    const int wave = tid >> 6;
    const int lane = tid & 63;
    const int wr = wave >> 1, wc = wave & 1;
    const int l15 = lane & 15, l4 = lane >> 4;

    const int mt = blockIdx.x;
    const int nt = col_tile_base + blockIdx.y;
    const int m0 = mt * BM;
    const int n0 = nt * BN;

    f32x4 acc[4][4];
#pragma unroll
    for (int i = 0; i < 4; ++i)
#pragma unroll
        for (int j = 0; j < 4; ++j) acc[i][j] = f32x4{0.f, 0.f, 0.f, 0.f};

    const int o0 = wave * 1024 + lane * 16;
    const int nk = Kdim >> 5;

    for (int kt = 0; kt < nk; ++kt) {
        const int k0 = kt << 5;
#pragma unroll
        for (int r = 0; r < 2; ++r) {
            int ob = o0 + r * 4096;
            int row = ob >> 6;
            int kb = ob & 63;
            const bf16_t* gA = A + (size_t)(m0 + row) * Kdim + k0 + (kb >> 1);
            GLL16(sA + ((wave * 1024 + r * 4096) >> 1), gA);
            const bf16_t* gB = BT + (size_t)(n0 + row) * Kdim + k0 + (kb >> 1);
            GLL16(sB + ((wave * 1024 + r * 4096) >> 1), gB);
        }
        __syncthreads();

        s16x8 af[4], bfr[4];
        const char* sAc = (const char*)sA;
        const char* sBc = (const char*)sB;
#pragma unroll
        for (int f = 0; f < 4; ++f) {
            af[f]  = *(const s16x8*)(sAc + (wr * 64 + f * 16 + l15) * 64 + l4 * 16);
            bfr[f] = *(const s16x8*)(sBc + (wc * 64 + f * 16 + l15) * 64 + l4 * 16);
        }
#pragma unroll
        for (int i = 0; i < 4; ++i)
#pragma unroll
            for (int j = 0; j < 4; ++j)
                acc[i][j] = __builtin_amdgcn_mfma_f32_16x16x32_bf16(af[i], bfr[j], acc[i][j], 0, 0, 0);
        __syncthreads();
    }

    if (nt < 24) {
        const int u = nt * 32 + wc * 16 + l15;
        float bi[4];
#pragma unroll
        for (int f = 0; f < 4; ++f) bi[f] = bias_r[n0 + wc * 64 + f * 16 + l15];
#pragma unroll
        for (int i = 0; i < 4; ++i) {
#pragma unroll
            for (int r = 0; r < 4; ++r) {
                int row = m0 + wr * 64 + i * 16 + l4 * 4 + r;
                float gi = acc[i][0][r] + bi[0];
                float gf = acc[i][1][r] + bi[1];
                float gg = acc[i][2][r] + bi[2];
                float go = acc[i][3][r] + bi[3];
                float si = sigf(gi);
                float sf = sigf(gf);
                float tg = tanh_fast(gg);
                float so = sigf(go);
                size_t cidx = (size_t)row * UNITS + u;
                float cold = is_first ? 0.f : c_state[cidx];
                float cn = sf * cold + si * tg;
                c_state[cidx] = cn;
                h_out[cidx] = (bf16_t)(so * tanh_fast(cn));
            }
        }
    } else {
#pragma unroll
        for (int f = 0; f < 4; ++f) {
            int j = wc * 64 + f * 16 + l15;
            if (j < NPRED) {
                float bd = b_d[j];
#pragma unroll
                for (int i = 0; i < 4; ++i)
#pragma unroll
                    for (int r = 0; r < 4; ++r) {
                        int row = m0 + wr * 64 + i * 16 + l4 * 4 + r;
                        out[((size_t)row * 64 + (t - 1)) * NPRED + j] = acc[i][f][r] + bd;
                    }
            }
        }
    }
}

extern "C" void kernel_launch(void* const* d_in, const int* in_sizes, int n_in,
                              void* d_out, int out_size, void* d_ws, size_t ws_size,
                              hipStream_t stream)
{
    const float* inputs = (const float*)d_in[0];
    const float* W_ih   = (const float*)d_in[1];
    const float* W_hh   = (const float*)d_in[2];
    const float* b_ih   = (const float*)d_in[3];
    const float* b_hh   = (const float*)d_in[4];
    const float* W_d    = (const float*)d_in[5];
    const float* b_d    = (const float*)d_in[6];
    float* out = (float*)d_out;

    char* ws = (char*)d_ws;
    size_t off = 0;
    auto alloc = [&](size_t bytes) -> char* {
        char* p = ws + off;
        off = (off + bytes + 255) & ~(size_t)255;
        return p;
    };
    bf16_t* B0T   = (bf16_t*)alloc((size_t)NCOLS * 96 * 2);
    bf16_t* BeffT = (bf16_t*)alloc((size_t)NPAD * UNITS * 2);
    bf16_t* x0    = (bf16_t*)alloc((size_t)MROWS * 96 * 2);
    bf16_t* h0    = (bf16_t*)alloc((size_t)MROWS * UNITS * 2);
    bf16_t* h1    = (bf16_t*)alloc((size_t)MROWS * UNITS * 2);
    float*  cst   = (float*)alloc((size_t)MROWS * UNITS * 4);
    float*  b0r   = (float*)alloc(NCOLS * 4);
    float*  beffr = (float*)alloc(NCOLS * 4);

    prep_b0   <<<(NCOLS * 96 + 255) / 256, 256, 0, stream>>>(W_ih, B0T);
    prep_x0   <<<(MROWS * 96) / 256, 256, 0, stream>>>(inputs, x0);
    prep_bias <<<(NCOLS + 255) / 256, 256, 0, stream>>>(b_ih, b_hh, W_ih, b_d, b0r, beffr);
    prep_beff2<<<dim3(48, 12), 256, 0, stream>>>(W_hh, W_ih, W_d, BeffT);
    prep_wdt  <<<(128 * UNITS) / 256, 256, 0, stream>>>(W_d, BeffT);

    // cooperative persistent kernel: 400 blocks (16 M-tiles x 25 N-tiles)
    void* x0v = (void*)x0; void* B0Tv = (void*)B0T; void* BeffTv = (void*)BeffT;
    void* b0rv = (void*)b0r; void* beffrv = (void*)beffr; void* bdv = (void*)b_d;
    void* h0v = (void*)h0; void* h1v = (void*)h1; void* outv = (void*)out;
    void* args[] = { &x0v, &B0Tv, &BeffTv, &b0rv, &beffrv, &bdv, &h0v, &h1v, &outv };

    hipError_t err = hipLaunchCooperativeKernel((const void*)persistent_kernel,
                                                dim3(400), dim3(256), args, 0, stream);
    if (err != hipSuccess) {
        (void)hipGetLastError();
        // fallback: verified per-step path
        bf16_t* h[2] = {h0, h1};
        step_kernel<<<dim3(16, 24), 256, 0, stream>>>(x0, B0T, b0r, b_d, cst, h[1], out,
                                                      96, 0, 0, 1);
        for (int n = 1; n < 64; ++n)
            step_kernel<<<dim3(16, 25), 256, 0, stream>>>(h[n & 1], BeffT, beffr, b_d, cst,
                                                          h[(n + 1) & 1], out, UNITS, 0, n, 0);
        step_kernel<<<dim3(16, 1), 256, 0, stream>>>(h[0], BeffT, beffr, b_d, cst, h[1], out,
                                                     UNITS, 24, 64, 0);
    }
    (void)cst; (void)ws_size; (void)in_sizes; (void)n_in; (void)out_size;
}

// Round 3
// 1352.997 us; speedup vs baseline: 5.1053x; 5.1053x over previous
//
#include <hip/hip_runtime.h>
#include <hip/hip_bf16.h>
#include <stdint.h>

typedef __hip_bfloat16 bf16_t;
typedef __attribute__((ext_vector_type(4))) float f32x4;
typedef __attribute__((ext_vector_type(8))) short s16x8;

#define UNITS 768
#define NCOLS 3072        // 4*UNITS (gates, reordered)
#define NPRED 96
#define NPAD  3200        // 25 tiles of 128
#define MROWS 2048
#define BM 128
#define BN 128
#define BK 32

// async global->LDS, 16B per lane, LDS dest = wave-uniform base + lane*16
#define GLL16(ldsp, gp) \
  __builtin_amdgcn_global_load_lds((const __attribute__((address_space(1))) void*)(gp), \
                                   (__attribute__((address_space(3))) void*)(ldsp), 16, 0, 0)

__device__ __forceinline__ float sigf(float x) {
    return __builtin_amdgcn_rcpf(1.f + __expf(-x));
}
__device__ __forceinline__ float tanh_fast(float x) {
    return 1.f - 2.f * __builtin_amdgcn_rcpf(1.f + __expf(2.f * x));
}

// ---------------- prep kernels (once per launch, off critical path) ---------------

// B0T[c][k] = W_ih[g*768+u][k], c-reordered, K=96
__global__ void prep_b0(const float* __restrict__ W_ih, bf16_t* __restrict__ B0T) {
    int idx = blockIdx.x * 256 + threadIdx.x;
    if (idx >= NCOLS * 96) return;
    int c = idx / 96, k = idx % 96;
    int u = ((c >> 6) << 4) + (c & 15);
    int g = (c >> 4) & 3;
    B0T[idx] = (bf16_t)W_ih[(g * UNITS + u) * 96 + k];
}

// x0[b][k] = inputs[b][23][k]
__global__ void prep_x0(const float* __restrict__ inputs, bf16_t* __restrict__ x0) {
    int idx = blockIdx.x * 256 + threadIdx.x; // < 2048*96 exactly
    int b = idx / 96, k = idx % 96;
    x0[idx] = (bf16_t)inputs[(b * 24 + 23) * 96 + k];
}

// b0_r[c] = b_ih+b_hh (reordered); beff_r[c] = b0_r + (W_ih @ b_d)
__global__ void prep_bias(const float* __restrict__ b_ih, const float* __restrict__ b_hh,
                          const float* __restrict__ W_ih, const float* __restrict__ b_d,
                          float* __restrict__ b0_r, float* __restrict__ beff_r) {
    int c = blockIdx.x * 256 + threadIdx.x;
    if (c >= NCOLS) return;
    int u = ((c >> 6) << 4) + (c & 15);
    int g = (c >> 4) & 3;
    int r = g * UNITS + u;
    float v = b_ih[r] + b_hh[r];
    float acc = 0.f;
    for (int j = 0; j < 96; ++j) acc += W_ih[r * 96 + j] * b_d[j];
    b0_r[c] = v;
    beff_r[c] = v + acc;
}

// BeffT[c][k] = W_hh[r(c)][k] + sum_j W_ih[r(c)][j]*W_d[j][k]   (c<3072, LDS-tiled)
__global__ void prep_beff2(const float* __restrict__ W_hh, const float* __restrict__ W_ih,
                           const float* __restrict__ W_d, bf16_t* __restrict__ BeffT) {
    __shared__ float sWih[64][96];
    __shared__ float sWd[96][64];
    const int c0 = blockIdx.x * 64, k0 = blockIdx.y * 64;
    const int tid = threadIdx.x;
    for (int i = tid; i < 64 * 96; i += 256) {
        int cc = i / 96, j = i % 96;
        int c = c0 + cc;
        int u = ((c >> 6) << 4) + (c & 15);
        int g = (c >> 4) & 3;
        sWih[cc][j] = W_ih[(g * UNITS + u) * 96 + j];
    }
    for (int i = tid; i < 96 * 64; i += 256) {
        int j = i / 64, kk = i % 64;
        sWd[j][kk] = W_d[j * UNITS + k0 + kk];
    }
    __syncthreads();
    const int kk = tid & 63;
    const int cc0 = (tid >> 6) * 16;
    for (int cc = cc0; cc < cc0 + 16; ++cc) {
        float acc = 0.f;
#pragma unroll 12
        for (int j = 0; j < 96; ++j) acc += sWih[cc][j] * sWd[j][kk];
        int c = c0 + cc;
        int u = ((c >> 6) << 4) + (c & 15);
        int g = (c >> 4) & 3;
        int r = g * UNITS + u;
        BeffT[(size_t)c * UNITS + k0 + kk] = (bf16_t)(W_hh[(size_t)r * UNITS + k0 + kk] + acc);
    }
}

// rows 3072..3199 of BeffT: W_d rows then zero pad
__global__ void prep_wdt(const float* __restrict__ W_d, bf16_t* __restrict__ BeffT) {
    int idx = blockIdx.x * 256 + threadIdx.x; // 128*768
    int c = idx / UNITS, k = idx % UNITS;
    float v = (c < NPRED) ? W_d[c * UNITS + k] : 0.f;
    BeffT[(size_t)(NCOLS + c) * UNITS + k] = (bf16_t)v;
}

// ---------------- main step kernel: single-barrier pipelined K-loop ---------------
// One GEMM (M=2048, N=tiles*128, K=Kdim) with fused LSTM-cell epilogue on gate tiles
// (nt<24) and pred store on tile 24.  A: M x K row-major bf16.  BT: N x K row-major bf16.
//
// Pipeline per kt: __syncthreads (drains buf[kt] staging); ds_read frags(buf[kt]);
// issue GLL16 stage for kt+1 into other buffer; MFMA. The kt+1 staging latency hides
// behind the MFMA block and is drained by the next iteration's barrier.
__global__ __launch_bounds__(256, 2)
void step_kernel(const bf16_t* __restrict__ A,
                 const bf16_t* __restrict__ BT,
                 const float* __restrict__ bias_r,
                 const float* __restrict__ b_d,
                 float* __restrict__ c_state,
                 bf16_t* __restrict__ h_out,
                 float* __restrict__ out,
                 int Kdim, int col_tile_base, int t, int is_first)
{
    __shared__ bf16_t sA0[BM * BK];
    __shared__ bf16_t sB0[BN * BK];
    __shared__ bf16_t sA1[BM * BK];
    __shared__ bf16_t sB1[BN * BK];

    const int tid = threadIdx.x;
    const int wave = tid >> 6;
    const int lane = tid & 63;
    const int wr = wave >> 1, wc = wave & 1;
    const int l15 = lane & 15, l4 = lane >> 4;

    const int mt = blockIdx.x;
    const int nt = col_tile_base + blockIdx.y;
    const int m0 = mt * BM;
    const int n0 = nt * BN;
    const bool is_pred = (nt >= 24);

    // ---- hoisted epilogue operands: c-state + biases load early, latency hides
    // behind the whole K-loop ----
    const int u = nt * 32 + wc * 16 + l15;
    float cold[16];
    float bi[4];
#pragma unroll
    for (int i = 0; i < 16; ++i) cold[i] = 0.f;
    if (!is_pred) {
        if (!is_first) {
#pragma unroll
            for (int i = 0; i < 4; ++i)
#pragma unroll
                for (int r = 0; r < 4; ++r)
                    cold[i * 4 + r] =
                        c_state[(size_t)(m0 + wr * 64 + i * 16 + l4 * 4 + r) * UNITS + u];
        }
#pragma unroll
        for (int f = 0; f < 4; ++f) bi[f] = bias_r[n0 + wc * 64 + f * 16 + l15];
    } else {
#pragma unroll
        for (int f = 0; f < 4; ++f) {
            int j = wc * 64 + f * 16 + l15;
            bi[f] = (j < NPRED) ? b_d[j] : 0.f;
        }
    }

    f32x4 acc[4][4];
#pragma unroll
    for (int i = 0; i < 4; ++i)
#pragma unroll
        for (int j = 0; j < 4; ++j) acc[i][j] = f32x4{0.f, 0.f, 0.f, 0.f};

    const int o0 = wave * 1024 + lane * 16;   // byte offset within 8KB tile
    const int nk = Kdim >> 5;

    // stage kt into (dstA, dstB)
#define STAGE(dstA, dstB, KT) do {                                                  \
        const int _k0 = (KT) << 5;                                                  \
        _Pragma("unroll")                                                           \
        for (int _r = 0; _r < 2; ++_r) {                                            \
            int _ob = o0 + _r * 4096;                                               \
            int _row = _ob >> 6;                                                    \
            int _kb = _ob & 63;                                                     \
            const bf16_t* _gA = A + (size_t)(m0 + _row) * Kdim + _k0 + (_kb >> 1);  \
            GLL16((dstA) + ((wave * 1024 + _r * 4096) >> 1), _gA);                  \
            const bf16_t* _gB = BT + (size_t)(n0 + _row) * Kdim + _k0 + (_kb >> 1); \
            GLL16((dstB) + ((wave * 1024 + _r * 4096) >> 1), _gB);                  \
        }                                                                           \
    } while (0)

    STAGE(sA0, sB0, 0);

    for (int kt = 0; kt < nk; ++kt) {
        __syncthreads();   // buf[kt] staging complete (all waves)

        const char* sAc = (kt & 1) ? (const char*)sA1 : (const char*)sA0;
        const char* sBc = (kt & 1) ? (const char*)sB1 : (const char*)sB0;

        s16x8 af[4], bfr[4];
#pragma unroll
        for (int f = 0; f < 4; ++f) {
            af[f]  = *(const s16x8*)(sAc + (wr * 64 + f * 16 + l15) * 64 + l4 * 16);
            bfr[f] = *(const s16x8*)(sBc + (wc * 64 + f * 16 + l15) * 64 + l4 * 16);
        }

        // issue next-tile staging into the other buffer; drains at next barrier
        if (kt + 1 < nk) {
            if (kt & 1) { STAGE(sA0, sB0, kt + 1); }
            else        { STAGE(sA1, sB1, kt + 1); }
        }

#pragma unroll
        for (int i = 0; i < 4; ++i)
#pragma unroll
            for (int j = 0; j < 4; ++j)
                acc[i][j] = __builtin_amdgcn_mfma_f32_16x16x32_bf16(af[i], bfr[j], acc[i][j], 0, 0, 0);
    }
#undef STAGE

    // ---- epilogue ----
    if (!is_pred) {
        // gate tile: lane's 4 fn-frags are gates i,f,g,o of unit u (column permutation)
#pragma unroll
        for (int i = 0; i < 4; ++i) {
#pragma unroll
            for (int r = 0; r < 4; ++r) {
                int row = m0 + wr * 64 + i * 16 + l4 * 4 + r;
                float gi = acc[i][0][r] + bi[0];
                float gf = acc[i][1][r] + bi[1];
                float gg = acc[i][2][r] + bi[2];
                float go = acc[i][3][r] + bi[3];
                float si = sigf(gi);
                float sf = sigf(gf);
                float tg = tanh_fast(gg);
                float so = sigf(go);
                size_t cidx = (size_t)row * UNITS + u;
                float cn = sf * cold[i * 4 + r] + si * tg;
                c_state[cidx] = cn;
                h_out[cidx] = (bf16_t)(so * tanh_fast(cn));
            }
        }
    } else {
        // pred tile: cols 3072..3167 are W_d rows -> out[:, t-1, :]
#pragma unroll
        for (int f = 0; f < 4; ++f) {
            int j = wc * 64 + f * 16 + l15;
            if (j < NPRED) {
#pragma unroll
                for (int i = 0; i < 4; ++i)
#pragma unroll
                    for (int r = 0; r < 4; ++r) {
                        int row = m0 + wr * 64 + i * 16 + l4 * 4 + r;
                        out[((size_t)row * 64 + (t - 1)) * NPRED + j] = acc[i][f][r] + bi[f];
                    }
            }
        }
    }
}

extern "C" void kernel_launch(void* const* d_in, const int* in_sizes, int n_in,
                              void* d_out, int out_size, void* d_ws, size_t ws_size,
                              hipStream_t stream)
{
    const float* inputs = (const float*)d_in[0];
    const float* W_ih   = (const float*)d_in[1];
    const float* W_hh   = (const float*)d_in[2];
    const float* b_ih   = (const float*)d_in[3];
    const float* b_hh   = (const float*)d_in[4];
    const float* W_d    = (const float*)d_in[5];
    const float* b_d    = (const float*)d_in[6];
    float* out = (float*)d_out;

    char* ws = (char*)d_ws;
    size_t off = 0;
    auto alloc = [&](size_t bytes) -> char* {
        char* p = ws + off;
        off = (off + bytes + 255) & ~(size_t)255;
        return p;
    };
    bf16_t* B0T   = (bf16_t*)alloc((size_t)NCOLS * 96 * 2);
    bf16_t* BeffT = (bf16_t*)alloc((size_t)NPAD * UNITS * 2);
    bf16_t* x0    = (bf16_t*)alloc((size_t)MROWS * 96 * 2);
    bf16_t* h0    = (bf16_t*)alloc((size_t)MROWS * UNITS * 2);
    bf16_t* h1    = (bf16_t*)alloc((size_t)MROWS * UNITS * 2);
    float*  cst   = (float*)alloc((size_t)MROWS * UNITS * 4);
    float*  b0r   = (float*)alloc(NCOLS * 4);
    float*  beffr = (float*)alloc(NCOLS * 4);

    prep_b0   <<<(NCOLS * 96 + 255) / 256, 256, 0, stream>>>(W_ih, B0T);
    prep_x0   <<<(MROWS * 96) / 256, 256, 0, stream>>>(inputs, x0);
    prep_bias <<<(NCOLS + 255) / 256, 256, 0, stream>>>(b_ih, b_hh, W_ih, b_d, b0r, beffr);
    prep_beff2<<<dim3(48, 12), 256, 0, stream>>>(W_hh, W_ih, W_d, BeffT);
    prep_wdt  <<<(128 * UNITS) / 256, 256, 0, stream>>>(W_d, BeffT);

    bf16_t* h[2] = {h0, h1};

    // iter 0: gates from x0 (K=96), h=c=0, no pred tile
    step_kernel<<<dim3(16, 24), 256, 0, stream>>>(x0, B0T, b0r, b_d, cst, h[1], out,
                                                  96, 0, 0, 1);
    // iters 1..63: gates_n = h_n @ W_eff^T (K=768) + pred_{n-1} columns
    for (int n = 1; n < 64; ++n)
        step_kernel<<<dim3(16, 25), 256, 0, stream>>>(h[n & 1], BeffT, beffr, b_d, cst,
                                                      h[(n + 1) & 1], out, UNITS, 0, n, 0);
    // tail: pred_63 = h_64 @ W_d^T + b_d  (pred tile only)
    step_kernel<<<dim3(16, 1), 256, 0, stream>>>(h[0], BeffT, beffr, b_d, cst, h[1], out,
                                                 UNITS, 24, 64, 0);
    (void)ws_size; (void)in_sizes; (void)n_in; (void)out_size;
}